// Round 3
// baseline (623.206 us; speedup 1.0000x reference)
//
#include <hip/hip_runtime.h>
#include <math.h>

#define BB 64
#define NN 1024
#define DD 1024

typedef __bf16 bf16x8 __attribute__((ext_vector_type(8)));
typedef _Float16 f16x8 __attribute__((ext_vector_type(8)));
typedef float f32x4 __attribute__((ext_vector_type(4)));
typedef unsigned short u16x8 __attribute__((ext_vector_type(8)));

#define GLOAD_LDS16(g, l)                                                  \
    __builtin_amdgcn_global_load_lds(                                      \
        (const __attribute__((address_space(1))) unsigned int*)(g),        \
        (__attribute__((address_space(3))) unsigned int*)(l), 16, 0, 0)

__device__ __forceinline__ float fast_tanh(float x) {
    return 1.f - 2.f / (__expf(2.f * x) + 1.f);
}

// ws layout:
//   qh      fp32 [BB*DD]                     @ 0
//   scores  fp32 [BB*NN]                     @ 65536 floats
//   wkT     fp16 [8 et][32 kt][128*32]       @ byte 524288   (2 MB)
//   keysT   fp16 [64 b][8 nt][32 kt][128*32] @ byte 2621440  (128 MB)
//
// SWIZZLE: within each 64-byte row of a [128][32]-f16 chunk, the four 16-byte
// sub-blocks are permuted: sub' = sub ^ ((row>>1)&3). Producer (k_cvt) writes
// pre-swizzled; k_sc stages linearly via global_load_lds and applies the same
// XOR on ds_read addresses (conflict-free b128); k_ctx relabels k-octets.

// ---- k_cvt: keys (and W_k as bb==64) fp32 -> fp16 tiled+swizzled chunks ----
__global__ __launch_bounds__(256) void k_cvt(const float* __restrict__ keys,
                                             const float* __restrict__ W_k,
                                             _Float16* __restrict__ keysT,
                                             _Float16* __restrict__ wkT) {
    const int nt = blockIdx.x;  // 8
    const int bb = blockIdx.y;  // 0..64 (64 = W_k)
    const int ks = blockIdx.z;  // 0..3
    const int t = threadIdx.x;
    const float* src = (bb == 64) ? (W_k + (size_t)nt * 128 * DD)
                                  : (keys + ((size_t)bb * NN + nt * 128) * DD);
    _Float16* dst = (bb == 64) ? (wkT + (size_t)nt * 32 * 4096)
                               : (keysT + (((size_t)bb * 8 + nt) * 32) * 4096);
    const int p0 = t * 8;
    const int n0 = p0 >> 5;      // row within 64-row half
    const int k0 = p0 & 31;      // k-octet start
    const int ksw = (k0 >> 3) ^ ((n0 >> 1) & 3);
    for (int kt = ks * 8; kt < ks * 8 + 8; ++kt) {
#pragma unroll
        for (int r = 0; r < 2; ++r) {
            const int n = n0 + r * 64;
            const float4* s4 = (const float4*)(src + (size_t)n * DD + kt * 32 + k0);
            float4 a = s4[0], b4 = s4[1];
            f16x8 h = {(_Float16)a.x,  (_Float16)a.y,  (_Float16)a.z,  (_Float16)a.w,
                       (_Float16)b4.x, (_Float16)b4.y, (_Float16)b4.z, (_Float16)b4.w};
            *(f16x8*)(dst + (size_t)kt * 4096 + n * 32 + ksw * 8) = h;
        }
    }
}

// ---- k_qh: qh[b, et*128..+128] = h_t[b] @ W_h.T slice; zeroes scores slice ----
__global__ __launch_bounds__(256) void k_qh(const float* __restrict__ h_t,
                                            const float* __restrict__ W_h,
                                            float* __restrict__ qh,
                                            float* __restrict__ scores) {
    __shared__ float hs[DD];
    __shared__ float red2[128];
    const int b = blockIdx.x;   // 0..63
    const int et = blockIdx.y;  // 0..7
    const int t = threadIdx.x;
    if (t < 128) scores[b * NN + et * 128 + t] = 0.f;
    ((float4*)hs)[t] = ((const float4*)(h_t + (size_t)b * DD))[t];
    __syncthreads();
    const int el = t & 127;
    const int half = t >> 7;
    const int e = et * 128 + el;
    const float4* wrow = (const float4*)(W_h + (size_t)e * DD) + half * 128;
    const float* hp = hs + half * 512;
    float acc = 0.f;
#pragma unroll 4
    for (int k4 = 0; k4 < 128; ++k4) {
        float4 wv = wrow[k4];
        acc = fmaf(wv.x, hp[4 * k4 + 0], acc);
        acc = fmaf(wv.y, hp[4 * k4 + 1], acc);
        acc = fmaf(wv.z, hp[4 * k4 + 2], acc);
        acc = fmaf(wv.w, hp[4 * k4 + 3], acc);
    }
    if (half == 1) red2[el] = acc;
    __syncthreads();
    if (half == 0) qh[(size_t)b * DD + e] = acc + red2[el];
}

// ---- k_sc: 256x256-tile fp16 MFMA GEMM, m201-style 8-phase pipeline ----
// grid 1024 (bijective XCD swizzle), 512 thr = 8 waves (2m x 4n), 128x64/wave.
// K-tiles of 64 (= 2 chunks of 32), 2-slot LDS double buffer (slot = tile&1).
// Per phase (16 MFMA = 4m x 4n at one k-step, one m-half):
//   [vmcnt(8) at tile-boundary phases only] -> s_barrier -> ds_read 4-8 b128
//   + issue 2 global_load_lds -> lgkmcnt(0) -> setprio(1) 16 MFMA setprio(0).
// Stage stream (iter t): q0/q1 stage tile t+1 kt1 chunks -> slot (t+1)&1
// (that kt1 region last read in iter t-1, >=1 barrier ago); q2/q3 stage tile
// t+2 kt0 -> slot t&1 (kt0 region fully read by end of phase q1 this iter).
// vmcnt(8) at q0 guarantees tile-t kt0 landed (8 loads issued after it);
// vmcnt(8) at q2 guarantees tile-t kt1. Tail peels to vmcnt(4)/vmcnt(0).
#define NOSTG do { } while (0)

#define STG2(APAN, BPAN, T, KT, SL, C)                                        \
    do {                                                                      \
        const size_t go_ = (size_t)((T) * 2 + (KT)) * 8192;                   \
        GLOAD_LDS16(APAN + go_, AsB + (SL) * 32768 + (C) * 8192 + tid * 16);  \
        GLOAD_LDS16(BPAN + go_, BsB + (SL) * 32768 + (C) * 8192 + tid * 16);  \
    } while (0)

#define PH(SL, KS, MH, LOADB, STG, VMW)                                       \
    do {                                                                      \
        if ((VMW) == 8) asm volatile("s_waitcnt vmcnt(8)" ::: "memory");      \
        else if ((VMW) == 4) asm volatile("s_waitcnt vmcnt(4)" ::: "memory"); \
        else if ((VMW) == 0) asm volatile("s_waitcnt vmcnt(0)" ::: "memory"); \
        __builtin_amdgcn_s_barrier();                                         \
        __builtin_amdgcn_sched_barrier(0);                                    \
        if (LOADB) {                                                          \
            _Pragma("unroll") for (int ni = 0; ni < 4; ++ni)                  \
                bf[ni] = *(const f16x8*)(Bs + (SL) * 16384 +                  \
                    ((KS) * 2 + beh) * 4096 + (brow + ni * 16) * 32 + qx8);   \
        }                                                                     \
        f16x8 af[4];                                                          \
        _Pragma("unroll") for (int mi = 0; mi < 4; ++mi)                      \
            af[mi] = *(const f16x8*)(As + (SL) * 16384 +                      \
                ((KS) * 2 + wm) * 4096 +                                      \
                ((MH) * 64 + mi * 16 + lcol) * 32 + qx8);                     \
        STG;                                                                  \
        asm volatile("s_waitcnt lgkmcnt(0)" ::: "memory");                    \
        __builtin_amdgcn_sched_barrier(0);                                    \
        __builtin_amdgcn_s_setprio(1);                                        \
        _Pragma("unroll") for (int mi = 0; mi < 4; ++mi)                      \
            _Pragma("unroll") for (int ni = 0; ni < 4; ++ni)                  \
                acc[(MH) * 4 + mi][ni] =                                      \
                    __builtin_amdgcn_mfma_f32_16x16x32_f16(                   \
                        af[mi], bf[ni], acc[(MH) * 4 + mi][ni], 0, 0, 0);     \
        __builtin_amdgcn_s_setprio(0);                                        \
        __builtin_amdgcn_sched_barrier(0);                                    \
    } while (0)

__global__ __launch_bounds__(512, 2) void k_sc(const _Float16* __restrict__ keysT,
                                               const _Float16* __restrict__ wkT,
                                               const float* __restrict__ v,
                                               const float* __restrict__ qh,
                                               float* __restrict__ scores) {
    __shared__ _Float16 As[2 * 16384];  // 2 slots x 4 chunks x 4096 f16 = 64 KB
    __shared__ _Float16 Bs[2 * 16384];  // 64 KB
    __shared__ float vs[256];
    __shared__ float qs[256];
    __shared__ float red[256][4];

    const int tid = threadIdx.x;
    const int gid = blockIdx.x;                     // 0..1023
    const int wg = (gid & 7) * 128 + (gid >> 3);    // bijective XCD chunking
    const int b = wg >> 4;                          // 0..63
    const int x = wg & 15;
    const int tn = x >> 2;                          // n-tile 0..3
    const int te = x & 3;                           // e-tile 0..3

    // issued FIRST: oldest vmem ops, drained before any counted vmcnt window
    if (tid < 256) {
        vs[tid] = v[te * 256 + tid];
        qs[tid] = qh[b * DD + te * 256 + tid];
    }

    // global panel bases (pre-swizzled chunks; chunk stride 8192 B)
    const char* a0 = (const char*)(keysT + (((size_t)b * 8 + tn * 2 + 0) * 32) * 4096) + tid * 16;
    const char* a1 = (const char*)(keysT + (((size_t)b * 8 + tn * 2 + 1) * 32) * 4096) + tid * 16;
    const char* b0 = (const char*)(wkT + (((size_t)te * 2 + 0) * 32) * 4096) + tid * 16;
    const char* b1 = (const char*)(wkT + (((size_t)te * 2 + 1) * 32) * 4096) + tid * 16;
    char* AsB = (char*)As;
    char* BsB = (char*)Bs;

    const int w = tid >> 6, lane = tid & 63;
    const int wm = w & 1, wn = w >> 1;
    const int lcol = lane & 15, quad = lane >> 4;
    const int qx8 = (quad ^ ((lcol >> 1) & 3)) * 8;  // read-side swizzle
    const int beh = wn >> 1;                         // B chunk e-half
    const int brow = (wn & 1) * 64 + lcol;           // B row base (+ ni*16)

    f32x4 acc[8][4];
#pragma unroll
    for (int mi = 0; mi < 8; ++mi)
#pragma unroll
        for (int ni = 0; ni < 4; ++ni) acc[mi][ni] = (f32x4){0.f, 0.f, 0.f, 0.f};
    f16x8 bf[4];

    // prologue: tile0 (8 loads), tile1 kt0 (4 loads) -- 12 in flight
    STG2(a0, b0, 0, 0, 0, 0);
    STG2(a1, b1, 0, 0, 0, 1);
    STG2(a0, b0, 0, 1, 0, 2);
    STG2(a1, b1, 0, 1, 0, 3);
    STG2(a0, b0, 1, 0, 1, 0);
    STG2(a1, b1, 1, 0, 1, 1);

#pragma unroll 1
    for (int t = 0; t < 14; ++t) {
        const int s = t & 1, s1 = s ^ 1;
        PH(s, 0, 0, 1, STG2(a0, b0, t + 1, 1, s1, 2), 8);
        PH(s, 0, 1, 0, STG2(a1, b1, t + 1, 1, s1, 3), -1);
        PH(s, 1, 0, 1, STG2(a0, b0, t + 2, 0, s, 0), 8);
        PH(s, 1, 1, 0, STG2(a1, b1, t + 2, 0, s, 1), -1);
    }
    // t = 14 (stage tile15 kt1 only)
    PH(0, 0, 0, 1, STG2(a0, b0, 15, 1, 1, 2), 8);
    PH(0, 0, 1, 0, STG2(a1, b1, 15, 1, 1, 3), -1);
    PH(0, 1, 0, 1, NOSTG, 8);
    PH(0, 1, 1, 0, NOSTG, -1);
    // t = 15 (no stages; drain 4 -> 0)
    PH(1, 0, 0, 1, NOSTG, 4);
    PH(1, 0, 1, 0, NOSTG, -1);
    PH(1, 1, 0, 1, NOSTG, 0);
    PH(1, 1, 1, 0, NOSTG, -1);

    // epilogue: C/D layout col=lane&15 (e), row=quad*4+reg (n)
    float part[8][4];
#pragma unroll
    for (int mi = 0; mi < 8; ++mi)
#pragma unroll
        for (int r = 0; r < 4; ++r) part[mi][r] = 0.f;
#pragma unroll
    for (int mi = 0; mi < 8; ++mi)
#pragma unroll
        for (int ni = 0; ni < 4; ++ni) {
            const int e = wn * 64 + ni * 16 + lcol;
            const float vv = vs[e];
            const float qv = qs[e];
#pragma unroll
            for (int r = 0; r < 4; ++r)
                part[mi][r] += vv * fast_tanh(qv + acc[mi][ni][r]);
        }
#pragma unroll
    for (int mi = 0; mi < 8; ++mi)
#pragma unroll
        for (int r = 0; r < 4; ++r) {
            float p = part[mi][r];
            p += __shfl_xor(p, 1);
            p += __shfl_xor(p, 2);
            p += __shfl_xor(p, 4);
            p += __shfl_xor(p, 8);
            if (lcol == 0) red[wm * 128 + mi * 16 + quad * 4 + r][wn] = p;
        }
    __syncthreads();
    if (tid < 256)
        atomicAdd(&scores[b * NN + tn * 256 + tid],
                  red[tid][0] + red[tid][1] + red[tid][2] + red[tid][3]);
}

// ---- k_sm: softmax ----
__global__ __launch_bounds__(256) void k_sm(const float* __restrict__ scores,
                                            float* __restrict__ alpha) {
    const int b = blockIdx.x;
    const int t = threadIdx.x;
    float x[4];
    float m = -1e30f;
#pragma unroll
    for (int j = 0; j < 4; ++j) {
        x[j] = scores[b * NN + t + 256 * j];
        m = fmaxf(m, x[j]);
    }
#pragma unroll
    for (int mask = 32; mask >= 1; mask >>= 1) m = fmaxf(m, __shfl_xor(m, mask));
    __shared__ float wred[4];
    __shared__ float wsum[4];
    const int wv = t >> 6;
    if ((t & 63) == 0) wred[wv] = m;
    __syncthreads();
    m = fmaxf(fmaxf(wred[0], wred[1]), fmaxf(wred[2], wred[3]));
    float s = 0.f;
#pragma unroll
    for (int j = 0; j < 4; ++j) {
        x[j] = expf(x[j] - m);
        s += x[j];
    }
#pragma unroll
    for (int mask = 32; mask >= 1; mask >>= 1) s += __shfl_xor(s, mask);
    if ((t & 63) == 0) wsum[wv] = s;
    __syncthreads();
    s = wsum[0] + wsum[1] + wsum[2] + wsum[3];
    const float inv = 1.f / s;
#pragma unroll
    for (int j = 0; j < 4; ++j) alpha[b * NN + t + 256 * j] = x[j] * inv;
}

// ---- k_ctx: context[b, kt*32..+32] = sum_n alpha[b,n]*keysT chunks ----
// Swizzle-aware: sub-block q of row g holds k-octet q ^ ((g>>1)&3).
__global__ __launch_bounds__(256) void k_ctx(const _Float16* __restrict__ keysT,
                                             const float* __restrict__ alpha,
                                             float* __restrict__ context) {
    __shared__ float al[NN];
    __shared__ float red[64][33];
    const int kt = blockIdx.x;  // 0..31
    const int b = blockIdx.y;   // 0..63
    const int t = threadIdx.x;
#pragma unroll
    for (int j = 0; j < 4; ++j) al[t + 256 * j] = alpha[b * NN + t + 256 * j];
    __syncthreads();

    const int p0 = t * 8;
    const int g = t >> 2;               // 0..63: n within half-chunk
    const int q = t & 3;                // physical sub-block
    const int qe = q ^ ((g >> 1) & 3);  // logical k-octet held
    float acc[8];
#pragma unroll
    for (int j = 0; j < 8; ++j) acc[j] = 0.f;

    for (int nt = 0; nt < 8; ++nt) {
        const _Float16* base = keysT + (((size_t)b * 8 + nt) * 32 + kt) * 4096;
#pragma unroll
        for (int r = 0; r < 2; ++r) {
            f16x8 kv = *(const f16x8*)(base + r * 2048 + p0);
            const float a = al[nt * 128 + r * 64 + g];
#pragma unroll
            for (int j = 0; j < 8; ++j) acc[j] = fmaf(a, (float)kv[j], acc[j]);
        }
    }
#pragma unroll
    for (int j = 0; j < 8; ++j) red[g][qe * 8 + j] = acc[j];
    __syncthreads();
    if (t < 32) {
        float s = 0.f;
#pragma unroll 8
        for (int n = 0; n < 64; ++n) s += red[n][t];
        context[(size_t)b * DD + kt * 32 + t] = s;
    }
}

// =========================== FALLBACK PATH (used if ws too small) ===========================
__global__ __launch_bounds__(256) void qh_fb(const float* __restrict__ h_t,
                                             const float* __restrict__ W_h,
                                             float* __restrict__ qh,
                                             float* __restrict__ scores) {
    __shared__ float hs[DD];
    const int b = blockIdx.y;
    const int e = blockIdx.x * 256 + threadIdx.x;
    scores[(blockIdx.y * 4 + blockIdx.x) * 256 + threadIdx.x] = 0.f;
    for (int i = threadIdx.x; i < DD; i += 256) hs[i] = h_t[b * DD + i];
    __syncthreads();
    const float4* wrow = (const float4*)(W_h + (size_t)e * DD);
    float acc = 0.f;
#pragma unroll 4
    for (int k4 = 0; k4 < DD / 4; ++k4) {
        float4 w = wrow[k4];
        acc = fmaf(w.x, hs[4 * k4 + 0], acc);
        acc = fmaf(w.y, hs[4 * k4 + 1], acc);
        acc = fmaf(w.z, hs[4 * k4 + 2], acc);
        acc = fmaf(w.w, hs[4 * k4 + 3], acc);
    }
    qh[b * DD + e] = acc;
}

#define SPAD 40
__device__ __forceinline__ void split16(const float4* __restrict__ src,
                                        unsigned short* hi, unsigned short* lo) {
    float x[16];
    float4 v0 = src[0], v1 = src[1], v2 = src[2], v3 = src[3];
    x[0] = v0.x; x[1] = v0.y; x[2] = v0.z; x[3] = v0.w;
    x[4] = v1.x; x[5] = v1.y; x[6] = v1.z; x[7] = v1.w;
    x[8] = v2.x; x[9] = v2.y; x[10] = v2.z; x[11] = v2.w;
    x[12] = v3.x; x[13] = v3.y; x[14] = v3.z; x[15] = v3.w;
#pragma unroll
    for (int i = 0; i < 16; ++i) {
        unsigned int u = __float_as_uint(x[i]);
        hi[i] = (unsigned short)(u >> 16);
        float hif = __uint_as_float(u & 0xFFFF0000u);
        float lof = x[i] - hif;
        lo[i] = (unsigned short)(__float_as_uint(lof) >> 16);
    }
}

__global__ __launch_bounds__(256, 2) void scores_fb(const float* __restrict__ keys,
                                                    const float* __restrict__ W_k,
                                                    const float* __restrict__ v,
                                                    const float* __restrict__ qh,
                                                    float* __restrict__ scores) {
    __shared__ unsigned short Ah[128 * SPAD];
    __shared__ unsigned short Al[128 * SPAD];
    __shared__ unsigned short Bh[128 * SPAD];
    __shared__ unsigned short Bl[128 * SPAD];
    __shared__ float vs[128];
    __shared__ float qs[128];
    __shared__ float red[128][2];

    const int tid = threadIdx.x;
    const int cp = blockIdx.x;
    const int rt = blockIdx.y;
    const int b = rt >> 3;
    const int n0 = (rt & 7) * 128;
    const int e0 = cp * 128;
    if (tid < 128) {
        vs[tid] = v[e0 + tid];
        qs[tid] = qh[b * DD + e0 + tid];
    }
    const float* Ag = keys + ((size_t)b * NN + n0) * DD;
    const float* Bg = W_k + (size_t)e0 * DD;
    const int w = tid >> 6;
    const int lane = tid & 63;
    const int wm = w & 1;
    const int we = w >> 1;
    const int lcol = lane & 15;
    const int quad = lane >> 4;
    f32x4 acc[4][4];
#pragma unroll
    for (int mi = 0; mi < 4; ++mi)
#pragma unroll
        for (int ni = 0; ni < 4; ++ni) acc[mi][ni] = (f32x4){0.f, 0.f, 0.f, 0.f};
    const int srow = tid >> 1;
    const int sseg = tid & 1;
    float4 pa[4], pb[4];
    {
        const float4* as = (const float4*)(Ag + (size_t)srow * DD + sseg * 16);
        const float4* bs = (const float4*)(Bg + (size_t)srow * DD + sseg * 16);
#pragma unroll
        for (int i = 0; i < 4; ++i) { pa[i] = as[i]; pb[i] = bs[i]; }
    }
    for (int kt = 0; kt < DD / 32; ++kt) {
        __syncthreads();
        {
            unsigned short hi[16], lo[16];
            split16(pa, hi, lo);
            u16x8* dh = (u16x8*)&Ah[srow * SPAD + sseg * 16];
            u16x8* dl = (u16x8*)&Al[srow * SPAD + sseg * 16];
            dh[0] = *(u16x8*)&hi[0]; dh[1] = *(u16x8*)&hi[8];
            dl[0] = *(u16x8*)&lo[0]; dl[1] = *(u16x8*)&lo[8];
            split16(pb, hi, lo);
            u16x8* eh = (u16x8*)&Bh[srow * SPAD + sseg * 16];
            u16x8* el = (u16x8*)&Bl[srow * SPAD + sseg * 16];
            eh[0] = *(u16x8*)&hi[0]; eh[1] = *(u16x8*)&hi[8];
            el[0] = *(u16x8*)&lo[0]; el[1] = *(u16x8*)&lo[8];
        }
        if (kt + 1 < DD / 32) {
            const int k0 = (kt + 1) * 32;
            const float4* as = (const float4*)(Ag + (size_t)srow * DD + k0 + sseg * 16);
            const float4* bs = (const float4*)(Bg + (size_t)srow * DD + k0 + sseg * 16);
#pragma unroll
            for (int i = 0; i < 4; ++i) { pa[i] = as[i]; pb[i] = bs[i]; }
        }
        __syncthreads();
        bf16x8 ah[4], al2[4], bh[4], bl2[4];
#pragma unroll
        for (int mi = 0; mi < 4; ++mi) {
            const int r = wm * 64 + mi * 16 + lcol;
            ah[mi] = *(const bf16x8*)&Ah[r * SPAD + quad * 8];
            al2[mi] = *(const bf16x8*)&Al[r * SPAD + quad * 8];
        }
#pragma unroll
        for (int ni = 0; ni < 4; ++ni) {
            const int r = we * 64 + ni * 16 + lcol;
            bh[ni] = *(const bf16x8*)&Bh[r * SPAD + quad * 8];
            bl2[ni] = *(const bf16x8*)&Bl[r * SPAD + quad * 8];
        }
#pragma unroll
        for (int mi = 0; mi < 4; ++mi)
#pragma unroll
            for (int ni = 0; ni < 4; ++ni) {
                acc[mi][ni] = __builtin_amdgcn_mfma_f32_16x16x32_bf16(ah[mi], bh[ni], acc[mi][ni], 0, 0, 0);
                acc[mi][ni] = __builtin_amdgcn_mfma_f32_16x16x32_bf16(ah[mi], bl2[ni], acc[mi][ni], 0, 0, 0);
                acc[mi][ni] = __builtin_amdgcn_mfma_f32_16x16x32_bf16(al2[mi], bh[ni], acc[mi][ni], 0, 0, 0);
            }
    }
    float part[4][4];
#pragma unroll
    for (int mi = 0; mi < 4; ++mi)
#pragma unroll
        for (int r = 0; r < 4; ++r) part[mi][r] = 0.f;
#pragma unroll
    for (int mi = 0; mi < 4; ++mi)
#pragma unroll
        for (int ni = 0; ni < 4; ++ni) {
            const int e = we * 64 + ni * 16 + lcol;
            const float vv = vs[e];
            const float qv = qs[e];
#pragma unroll
            for (int r = 0; r < 4; ++r)
                part[mi][r] += vv * fast_tanh(qv + acc[mi][ni][r]);
        }
#pragma unroll
    for (int mi = 0; mi < 4; ++mi)
#pragma unroll
        for (int r = 0; r < 4; ++r) {
            float p = part[mi][r];
            p += __shfl_xor(p, 1);
            p += __shfl_xor(p, 2);
            p += __shfl_xor(p, 4);
            p += __shfl_xor(p, 8);
            if (lcol == 0) red[wm * 64 + mi * 16 + quad * 4 + r][we] = p;
        }
    __syncthreads();
    if (tid < 128) atomicAdd(&scores[b * NN + n0 + tid], red[tid][0] + red[tid][1]);
}

__global__ __launch_bounds__(256) void sm_fb(const float* __restrict__ scores,
                                             float* __restrict__ alpha,
                                             float* __restrict__ context) {
    const int b = blockIdx.x;
    const int t = threadIdx.x;
#pragma unroll
    for (int j = 0; j < 4; ++j) context[b * DD + t + 256 * j] = 0.f;
    float x[4];
    float m = -1e30f;
#pragma unroll
    for (int j = 0; j < 4; ++j) {
        x[j] = scores[b * NN + t + 256 * j];
        m = fmaxf(m, x[j]);
    }
#pragma unroll
    for (int mask = 32; mask >= 1; mask >>= 1) m = fmaxf(m, __shfl_xor(m, mask));
    __shared__ float wred[4];
    __shared__ float wsum[4];
    const int wv = t >> 6;
    if ((t & 63) == 0) wred[wv] = m;
    __syncthreads();
    m = fmaxf(fmaxf(wred[0], wred[1]), fmaxf(wred[2], wred[3]));
    float s = 0.f;
#pragma unroll
    for (int j = 0; j < 4; ++j) {
        x[j] = expf(x[j] - m);
        s += x[j];
    }
#pragma unroll
    for (int mask = 32; mask >= 1; mask >>= 1) s += __shfl_xor(s, mask);
    if ((t & 63) == 0) wsum[wv] = s;
    __syncthreads();
    s = wsum[0] + wsum[1] + wsum[2] + wsum[3];
    const float inv = 1.f / s;
#pragma unroll
    for (int j = 0; j < 4; ++j) alpha[b * NN + t + 256 * j] = x[j] * inv;
}

__global__ __launch_bounds__(256) void ctx_fb(const float* __restrict__ keys,
                                              const float* __restrict__ alpha,
                                              float* __restrict__ context) {
    const int b = blockIdx.y;
    const int nc = blockIdx.x;
    const int t = threadIdx.x;
    __shared__ float al[64];
    if (t < 64) al[t] = alpha[b * NN + nc * 64 + t];
    __syncthreads();
    const float4* kp = (const float4*)(keys + ((size_t)b * NN + nc * 64) * DD);
    float4 acc = {0.f, 0.f, 0.f, 0.f};
#pragma unroll 4
    for (int n = 0; n < 64; ++n) {
        const float a = al[n];
        float4 kv = kp[(size_t)n * (DD / 4) + t];
        acc.x = fmaf(a, kv.x, acc.x);
        acc.y = fmaf(a, kv.y, acc.y);
        acc.z = fmaf(a, kv.z, acc.z);
        acc.w = fmaf(a, kv.w, acc.w);
    }
    float* cp = context + b * DD + 4 * t;
    atomicAdd(cp + 0, acc.x);
    atomicAdd(cp + 1, acc.y);
    atomicAdd(cp + 2, acc.z);
    atomicAdd(cp + 3, acc.w);
}

extern "C" void kernel_launch(void* const* d_in, const int* in_sizes, int n_in,
                              void* d_out, int out_size, void* d_ws, size_t ws_size,
                              hipStream_t stream) {
    const float* h_t = (const float*)d_in[0];
    const float* keys = (const float*)d_in[1];
    const float* W_h = (const float*)d_in[2];
    const float* W_k = (const float*)d_in[3];
    const float* v = (const float*)d_in[4];

    float* context = (float*)d_out;          // [B, D]
    float* alpha = (float*)d_out + BB * DD;  // [B, N]
    float* qh = (float*)d_ws;                // [B, D]
    float* scores = (float*)d_ws + BB * DD;  // [B, N]

    const size_t wkT_off = (size_t)2 * BB * DD * sizeof(float);  // 512 KB
    const size_t keysT_off = wkT_off + (size_t)DD * DD * 2;      // +2 MB
    const size_t need = keysT_off + (size_t)BB * NN * DD * 2;    // +128 MB

    if (ws_size >= need) {
        _Float16* wkT = (_Float16*)((char*)d_ws + wkT_off);
        _Float16* keysT = (_Float16*)((char*)d_ws + keysT_off);
        k_cvt<<<dim3(8, 65, 4), 256, 0, stream>>>(keys, W_k, keysT, wkT);
        k_qh<<<dim3(64, 8), 256, 0, stream>>>(h_t, W_h, qh, scores);
        k_sc<<<dim3(1024), 512, 0, stream>>>(keysT, wkT, v, qh, scores);
        k_sm<<<BB, 256, 0, stream>>>(scores, alpha);
        k_ctx<<<dim3(32, 64), 256, 0, stream>>>(keysT, alpha, context);
    } else {
        qh_fb<<<dim3(4, BB), 256, 0, stream>>>(h_t, W_h, qh, scores);
        scores_fb<<<dim3(8, 512), 256, 0, stream>>>(keys, W_k, v, qh, scores);
        sm_fb<<<BB, 256, 0, stream>>>(scores, alpha, context);
        ctx_fb<<<dim3(16, BB), 256, 0, stream>>>(keys, alpha, context);
    }
}

// Round 4
// 605.766 us; speedup vs baseline: 1.0288x; 1.0288x over previous
//
#include <hip/hip_runtime.h>
#include <math.h>

#define BB 64
#define NN 1024
#define DD 1024

typedef __bf16 bf16x8 __attribute__((ext_vector_type(8)));
typedef _Float16 f16x8 __attribute__((ext_vector_type(8)));
typedef float f32x4 __attribute__((ext_vector_type(4)));
typedef unsigned short u16x8 __attribute__((ext_vector_type(8)));

#define GLOAD_LDS16(g, l)                                                  \
    __builtin_amdgcn_global_load_lds(                                      \
        (const __attribute__((address_space(1))) unsigned int*)(g),        \
        (__attribute__((address_space(3))) unsigned int*)(l), 16, 0, 0)

__device__ __forceinline__ float fast_tanh(float x) {
    return 1.f - 2.f / (__expf(2.f * x) + 1.f);
}

// ws layout (shrunk: keysT deleted, keys is read fp32 directly):
//   qh      fp32 [BB*DD]               @ 0
//   scores  fp32 [BB*NN]               @ 65536 floats
//   wkT     fp16 [8 et][32 kt][128*32] @ byte 524288   (2 MB)
//
// wkT chunk swizzle (unchanged): within each 64-B row of a [128][32]-f16
// chunk, sub' = sub ^ ((row>>1)&3). k_wk writes pre-swizzled; k_scf stages
// linearly via global_load_lds and XORs the ds_read address (conflict-free).

// ---- k_wk: W_k fp32 -> fp16 tiled+swizzled chunks (2 MB only, ~3 us) ----
__global__ __launch_bounds__(256) void k_wk(const float* __restrict__ W_k,
                                            _Float16* __restrict__ wkT) {
    const int et = blockIdx.x;  // 8
    const int ks = blockIdx.y;  // 0..3
    const int t = threadIdx.x;
    const float* src = W_k + (size_t)et * 128 * DD;
    _Float16* dst = wkT + (size_t)et * 32 * 4096;
    const int p0 = t * 8;
    const int n0 = p0 >> 5;
    const int k0 = p0 & 31;
    const int ksw = (k0 >> 3) ^ ((n0 >> 1) & 3);
    for (int kt = ks * 8; kt < ks * 8 + 8; ++kt) {
#pragma unroll
        for (int r = 0; r < 2; ++r) {
            const int n = n0 + r * 64;
            const float4* s4 = (const float4*)(src + (size_t)n * DD + kt * 32 + k0);
            float4 a = s4[0], b4 = s4[1];
            f16x8 h = {(_Float16)a.x,  (_Float16)a.y,  (_Float16)a.z,  (_Float16)a.w,
                       (_Float16)b4.x, (_Float16)b4.y, (_Float16)b4.z, (_Float16)b4.w};
            *(f16x8*)(dst + (size_t)kt * 4096 + n * 32 + ksw * 8) = h;
        }
    }
}

// ---- k_qh: qh[b, et*128..+128] = h_t[b] @ W_h.T slice; zeroes scores slice ----
__global__ __launch_bounds__(256) void k_qh(const float* __restrict__ h_t,
                                            const float* __restrict__ W_h,
                                            float* __restrict__ qh,
                                            float* __restrict__ scores) {
    __shared__ float hs[DD];
    __shared__ float red2[128];
    const int b = blockIdx.x;   // 0..63
    const int et = blockIdx.y;  // 0..7
    const int t = threadIdx.x;
    if (t < 128) scores[b * NN + et * 128 + t] = 0.f;
    ((float4*)hs)[t] = ((const float4*)(h_t + (size_t)b * DD))[t];
    __syncthreads();
    const int el = t & 127;
    const int half = t >> 7;
    const int e = et * 128 + el;
    const float4* wrow = (const float4*)(W_h + (size_t)e * DD) + half * 128;
    const float* hp = hs + half * 512;
    float acc = 0.f;
#pragma unroll 4
    for (int k4 = 0; k4 < 128; ++k4) {
        float4 wv = wrow[k4];
        acc = fmaf(wv.x, hp[4 * k4 + 0], acc);
        acc = fmaf(wv.y, hp[4 * k4 + 1], acc);
        acc = fmaf(wv.z, hp[4 * k4 + 2], acc);
        acc = fmaf(wv.w, hp[4 * k4 + 3], acc);
    }
    if (half == 1) red2[el] = acc;
    __syncthreads();
    if (half == 0) qh[(size_t)b * DD + e] = acc + red2[el];
}

// ---- k_scf: FUSED keys-fp32 -> f16 MFMA GEMM + tanh/v epilogue ----
// R1's proven 128x128 structure (256 thr, 4 waves, ~3-4 blocks/CU).
// A: keys fp32 reg-prefetch (T14) -> cvt -> ds_write into SPAD=40 padded LDS.
// B: wkT fp16 via global_load_lds, 2-slot double buffer, counted vmcnt(6).
// grid (64, 64): bx = cp*8 + nt (same-A blocks -> same XCD), by = b.
#define SPAD2 40
__global__ __launch_bounds__(256, 3) void k_scf(const float* __restrict__ keys,
                                                const _Float16* __restrict__ wkT,
                                                const float* __restrict__ v,
                                                const float* __restrict__ qh,
                                                float* __restrict__ scores) {
    __shared__ _Float16 As[128 * SPAD2];  // 10 KB
    __shared__ _Float16 Bs[2 * 4096];     // 16 KB, 2 slots
    __shared__ float vs[128];
    __shared__ float qs[128];
    __shared__ float red[128][2];

    const int tid = threadIdx.x;
    const int cp = blockIdx.x >> 3;  // e-tile 0..7
    const int nt = blockIdx.x & 7;   // n-tile 0..7
    const int b = blockIdx.y;
    const int e0 = cp * 128;

    // issued first so the compiler's wait for the vs/qs ds_write drains only these
    if (tid < 128) {
        vs[tid] = v[e0 + tid];
        qs[tid] = qh[b * DD + e0 + tid];
    }

    const float* Ag = keys + ((size_t)b * NN + nt * 128) * DD;
    const char* Bg = (const char*)(wkT + (size_t)cp * 32 * 4096) + tid * 16;
    char* BsB = (char*)Bs;

    const int w = tid >> 6, lane = tid & 63;
    const int wm = w & 1, we = w >> 1;
    const int lcol = lane & 15, quad = lane >> 4;
    const int qx8 = (quad ^ ((lcol >> 1) & 3)) * 8;  // B read-side swizzle
    const int srow = tid >> 1, sseg = tid & 1;
    const float* Ap = Ag + (size_t)srow * DD + sseg * 16;

    f32x4 acc[4][4];
#pragma unroll
    for (int mi = 0; mi < 4; ++mi)
#pragma unroll
        for (int ni = 0; ni < 4; ++ni) acc[mi][ni] = (f32x4){0.f, 0.f, 0.f, 0.f};

    // prologue: prefetch A(0) regs, stage B(0) -> slot0
    float4 pa[4];
#pragma unroll
    for (int i = 0; i < 4; ++i) pa[i] = ((const float4*)Ap)[i];
    GLOAD_LDS16(Bg, BsB + tid * 16);
    GLOAD_LDS16(Bg + 4096, BsB + 4096 + tid * 16);

#pragma unroll 1
    for (int kt = 0; kt < 32; ++kt) {
        const int slot = kt & 1;
        __builtin_amdgcn_s_barrier();  // readers of As(kt-1)/Bs(slot^1 from kt-1) done
        __builtin_amdgcn_sched_barrier(0);
        // convert A(kt) regs -> LDS (compiler inserts the vmcnt for pa)
        f16x8 h0 = {(_Float16)pa[0].x, (_Float16)pa[0].y, (_Float16)pa[0].z, (_Float16)pa[0].w,
                    (_Float16)pa[1].x, (_Float16)pa[1].y, (_Float16)pa[1].z, (_Float16)pa[1].w};
        f16x8 h1 = {(_Float16)pa[2].x, (_Float16)pa[2].y, (_Float16)pa[2].z, (_Float16)pa[2].w,
                    (_Float16)pa[3].x, (_Float16)pa[3].y, (_Float16)pa[3].z, (_Float16)pa[3].w};
        *(f16x8*)&As[srow * SPAD2 + sseg * 16] = h0;
        *(f16x8*)&As[srow * SPAD2 + sseg * 16 + 8] = h1;
        if (kt + 1 < 32) {
            // prefetch A(kt+1) regs + stage B(kt+1) -> other slot
            const float* Apn = Ap + (kt + 1) * 32;
#pragma unroll
            for (int i = 0; i < 4; ++i) pa[i] = ((const float4*)Apn)[i];
            GLOAD_LDS16(Bg + (size_t)(kt + 1) * 8192, BsB + (slot ^ 1) * 8192 + tid * 16);
            GLOAD_LDS16(Bg + (size_t)(kt + 1) * 8192 + 4096,
                        BsB + (slot ^ 1) * 8192 + 4096 + tid * 16);
            // 6 newest (4 pa + 2 gload) may stay in flight; B(kt) + older drained
            asm volatile("s_waitcnt vmcnt(6) lgkmcnt(0)" ::: "memory");
        } else {
            asm volatile("s_waitcnt vmcnt(0) lgkmcnt(0)" ::: "memory");
        }
        __builtin_amdgcn_s_barrier();
        __builtin_amdgcn_sched_barrier(0);

        f16x8 af[4], bf[4];
#pragma unroll
        for (int mi = 0; mi < 4; ++mi)
            af[mi] = *(const f16x8*)&As[(wm * 64 + mi * 16 + lcol) * SPAD2 + quad * 8];
#pragma unroll
        for (int ni = 0; ni < 4; ++ni)
            bf[ni] = *(const f16x8*)&Bs[slot * 4096 + (we * 64 + ni * 16 + lcol) * 32 + qx8];
        asm volatile("s_waitcnt lgkmcnt(0)" ::: "memory");
        __builtin_amdgcn_sched_barrier(0);
        __builtin_amdgcn_s_setprio(1);
#pragma unroll
        for (int mi = 0; mi < 4; ++mi)
#pragma unroll
            for (int ni = 0; ni < 4; ++ni)
                acc[mi][ni] = __builtin_amdgcn_mfma_f32_16x16x32_f16(af[mi], bf[ni], acc[mi][ni], 0, 0, 0);
        __builtin_amdgcn_s_setprio(0);
        __builtin_amdgcn_sched_barrier(0);
    }

    // epilogue: C/D layout col=lane&15 (e), row=quad*4+reg (n)
    float part[4][4];
#pragma unroll
    for (int mi = 0; mi < 4; ++mi)
#pragma unroll
        for (int r = 0; r < 4; ++r) part[mi][r] = 0.f;
#pragma unroll
    for (int mi = 0; mi < 4; ++mi)
#pragma unroll
        for (int ni = 0; ni < 4; ++ni) {
            const int e = we * 64 + ni * 16 + lcol;
            const float vv = vs[e];
            const float qv = qs[e];
#pragma unroll
            for (int r = 0; r < 4; ++r)
                part[mi][r] += vv * fast_tanh(qv + acc[mi][ni][r]);
        }
#pragma unroll
    for (int mi = 0; mi < 4; ++mi)
#pragma unroll
        for (int r = 0; r < 4; ++r) {
            float p = part[mi][r];
            p += __shfl_xor(p, 1);
            p += __shfl_xor(p, 2);
            p += __shfl_xor(p, 4);
            p += __shfl_xor(p, 8);
            if (lcol == 0) red[wm * 64 + mi * 16 + quad * 4 + r][we] = p;
        }
    __syncthreads();
    if (tid < 128) atomicAdd(&scores[b * NN + nt * 128 + tid], red[tid][0] + red[tid][1]);
}

// ---- k_sm: softmax ----
__global__ __launch_bounds__(256) void k_sm(const float* __restrict__ scores,
                                            float* __restrict__ alpha) {
    const int b = blockIdx.x;
    const int t = threadIdx.x;
    float x[4];
    float m = -1e30f;
#pragma unroll
    for (int j = 0; j < 4; ++j) {
        x[j] = scores[b * NN + t + 256 * j];
        m = fmaxf(m, x[j]);
    }
#pragma unroll
    for (int mask = 32; mask >= 1; mask >>= 1) m = fmaxf(m, __shfl_xor(m, mask));
    __shared__ float wred[4];
    __shared__ float wsum[4];
    const int wv = t >> 6;
    if ((t & 63) == 0) wred[wv] = m;
    __syncthreads();
    m = fmaxf(fmaxf(wred[0], wred[1]), fmaxf(wred[2], wred[3]));
    float s = 0.f;
#pragma unroll
    for (int j = 0; j < 4; ++j) {
        x[j] = expf(x[j] - m);
        s += x[j];
    }
#pragma unroll
    for (int mask = 32; mask >= 1; mask >>= 1) s += __shfl_xor(s, mask);
    if ((t & 63) == 0) wsum[wv] = s;
    __syncthreads();
    s = wsum[0] + wsum[1] + wsum[2] + wsum[3];
    const float inv = 1.f / s;
#pragma unroll
    for (int j = 0; j < 4; ++j) alpha[b * NN + t + 256 * j] = x[j] * inv;
}

// ---- k_ctx: context[b, dc*64..+64] = sum_n alpha[b,n]*keys[b,n,:] (fp32 direct) ----
// grid (16 dc, 64 b). Wave reads 4 rows x 256 B contiguous; 16-way n-split reduce.
__global__ __launch_bounds__(256) void k_ctx(const float* __restrict__ keys,
                                             const float* __restrict__ alpha,
                                             float* __restrict__ context) {
    __shared__ float al[NN];
    __shared__ float red[16][72];
    const int dc = blockIdx.x;  // 0..15
    const int b = blockIdx.y;   // 0..63
    const int t = threadIdx.x;
#pragma unroll
    for (int j = 0; j < 4; ++j) al[t + 256 * j] = alpha[b * NN + t + 256 * j];
    __syncthreads();

    const int ng = t >> 4;  // 0..15: n-subset
    const int dq = t & 15;  // column quad within the 64-col block
    const float* kp = keys + (size_t)b * NN * DD + dc * 64 + dq * 4;
    float4 acc = {0.f, 0.f, 0.f, 0.f};
#pragma unroll 4
    for (int i = 0; i < 64; ++i) {
        const int n = i * 16 + ng;
        float4 kv = *(const float4*)(kp + (size_t)n * DD);
        const float a = al[n];
        acc.x = fmaf(a, kv.x, acc.x);
        acc.y = fmaf(a, kv.y, acc.y);
        acc.z = fmaf(a, kv.z, acc.z);
        acc.w = fmaf(a, kv.w, acc.w);
    }
    *(float4*)&red[ng][dq * 4] = acc;
    __syncthreads();
    if (t < 64) {
        float s = 0.f;
#pragma unroll
        for (int g = 0; g < 16; ++g) s += red[g][t];
        context[(size_t)b * DD + dc * 64 + t] = s;
    }
}

// =========================== FALLBACK PATH (used if ws too small) ===========================
__global__ __launch_bounds__(256) void qh_fb(const float* __restrict__ h_t,
                                             const float* __restrict__ W_h,
                                             float* __restrict__ qh,
                                             float* __restrict__ scores) {
    __shared__ float hs[DD];
    const int b = blockIdx.y;
    const int e = blockIdx.x * 256 + threadIdx.x;
    scores[(blockIdx.y * 4 + blockIdx.x) * 256 + threadIdx.x] = 0.f;
    for (int i = threadIdx.x; i < DD; i += 256) hs[i] = h_t[b * DD + i];
    __syncthreads();
    const float4* wrow = (const float4*)(W_h + (size_t)e * DD);
    float acc = 0.f;
#pragma unroll 4
    for (int k4 = 0; k4 < DD / 4; ++k4) {
        float4 w = wrow[k4];
        acc = fmaf(w.x, hs[4 * k4 + 0], acc);
        acc = fmaf(w.y, hs[4 * k4 + 1], acc);
        acc = fmaf(w.z, hs[4 * k4 + 2], acc);
        acc = fmaf(w.w, hs[4 * k4 + 3], acc);
    }
    qh[b * DD + e] = acc;
}

#define SPAD 40
__device__ __forceinline__ void split16(const float4* __restrict__ src,
                                        unsigned short* hi, unsigned short* lo) {
    float x[16];
    float4 v0 = src[0], v1 = src[1], v2 = src[2], v3 = src[3];
    x[0] = v0.x; x[1] = v0.y; x[2] = v0.z; x[3] = v0.w;
    x[4] = v1.x; x[5] = v1.y; x[6] = v1.z; x[7] = v1.w;
    x[8] = v2.x; x[9] = v2.y; x[10] = v2.z; x[11] = v2.w;
    x[12] = v3.x; x[13] = v3.y; x[14] = v3.z; x[15] = v3.w;
#pragma unroll
    for (int i = 0; i < 16; ++i) {
        unsigned int u = __float_as_uint(x[i]);
        hi[i] = (unsigned short)(u >> 16);
        float hif = __uint_as_float(u & 0xFFFF0000u);
        float lof = x[i] - hif;
        lo[i] = (unsigned short)(__float_as_uint(lof) >> 16);
    }
}

__global__ __launch_bounds__(256, 2) void scores_fb(const float* __restrict__ keys,
                                                    const float* __restrict__ W_k,
                                                    const float* __restrict__ v,
                                                    const float* __restrict__ qh,
                                                    float* __restrict__ scores) {
    __shared__ unsigned short Ah[128 * SPAD];
    __shared__ unsigned short Al[128 * SPAD];
    __shared__ unsigned short Bh[128 * SPAD];
    __shared__ unsigned short Bl[128 * SPAD];
    __shared__ float vs[128];
    __shared__ float qs[128];
    __shared__ float red[128][2];

    const int tid = threadIdx.x;
    const int cp = blockIdx.x;
    const int rt = blockIdx.y;
    const int b = rt >> 3;
    const int n0 = (rt & 7) * 128;
    const int e0 = cp * 128;
    if (tid < 128) {
        vs[tid] = v[e0 + tid];
        qs[tid] = qh[b * DD + e0 + tid];
    }
    const float* Ag = keys + ((size_t)b * NN + n0) * DD;
    const float* Bg = W_k + (size_t)e0 * DD;
    const int w = tid >> 6;
    const int lane = tid & 63;
    const int wm = w & 1;
    const int we = w >> 1;
    const int lcol = lane & 15;
    const int quad = lane >> 4;
    f32x4 acc[4][4];
#pragma unroll
    for (int mi = 0; mi < 4; ++mi)
#pragma unroll
        for (int ni = 0; ni < 4; ++ni) acc[mi][ni] = (f32x4){0.f, 0.f, 0.f, 0.f};
    const int srow = tid >> 1;
    const int sseg = tid & 1;
    float4 pa[4], pb[4];
    {
        const float4* as = (const float4*)(Ag + (size_t)srow * DD + sseg * 16);
        const float4* bs = (const float4*)(Bg + (size_t)srow * DD + sseg * 16);
#pragma unroll
        for (int i = 0; i < 4; ++i) { pa[i] = as[i]; pb[i] = bs[i]; }
    }
    for (int kt = 0; kt < DD / 32; ++kt) {
        __syncthreads();
        {
            unsigned short hi[16], lo[16];
            split16(pa, hi, lo);
            u16x8* dh = (u16x8*)&Ah[srow * SPAD + sseg * 16];
            u16x8* dl = (u16x8*)&Al[srow * SPAD + sseg * 16];
            dh[0] = *(u16x8*)&hi[0]; dh[1] = *(u16x8*)&hi[8];
            dl[0] = *(u16x8*)&lo[0]; dl[1] = *(u16x8*)&lo[8];
            split16(pb, hi, lo);
            u16x8* eh = (u16x8*)&Bh[srow * SPAD + sseg * 16];
            u16x8* el = (u16x8*)&Bl[srow * SPAD + sseg * 16];
            eh[0] = *(u16x8*)&hi[0]; eh[1] = *(u16x8*)&hi[8];
            el[0] = *(u16x8*)&lo[0]; el[1] = *(u16x8*)&lo[8];
        }
        if (kt + 1 < DD / 32) {
            const int k0 = (kt + 1) * 32;
            const float4* as = (const float4*)(Ag + (size_t)srow * DD + k0 + sseg * 16);
            const float4* bs = (const float4*)(Bg + (size_t)srow * DD + k0 + sseg * 16);
#pragma unroll
            for (int i = 0; i < 4; ++i) { pa[i] = as[i]; pb[i] = bs[i]; }
        }
        __syncthreads();
        bf16x8 ah[4], al2[4], bh[4], bl2[4];
#pragma unroll
        for (int mi = 0; mi < 4; ++mi) {
            const int r = wm * 64 + mi * 16 + lcol;
            ah[mi] = *(const bf16x8*)&Ah[r * SPAD + quad * 8];
            al2[mi] = *(const bf16x8*)&Al[r * SPAD + quad * 8];
        }
#pragma unroll
        for (int ni = 0; ni < 4; ++ni) {
            const int r = we * 64 + ni * 16 + lcol;
            bh[ni] = *(const bf16x8*)&Bh[r * SPAD + quad * 8];
            bl2[ni] = *(const bf16x8*)&Bl[r * SPAD + quad * 8];
        }
#pragma unroll
        for (int mi = 0; mi < 4; ++mi)
#pragma unroll
            for (int ni = 0; ni < 4; ++ni) {
                acc[mi][ni] = __builtin_amdgcn_mfma_f32_16x16x32_bf16(ah[mi], bh[ni], acc[mi][ni], 0, 0, 0);
                acc[mi][ni] = __builtin_amdgcn_mfma_f32_16x16x32_bf16(ah[mi], bl2[ni], acc[mi][ni], 0, 0, 0);
                acc[mi][ni] = __builtin_amdgcn_mfma_f32_16x16x32_bf16(al2[mi], bh[ni], acc[mi][ni], 0, 0, 0);
            }
    }
    float part[4][4];
#pragma unroll
    for (int mi = 0; mi < 4; ++mi)
#pragma unroll
        for (int r = 0; r < 4; ++r) part[mi][r] = 0.f;
#pragma unroll
    for (int mi = 0; mi < 4; ++mi)
#pragma unroll
        for (int ni = 0; ni < 4; ++ni) {
            const int e = we * 64 + ni * 16 + lcol;
            const float vv = vs[e];
            const float qv = qs[e];
#pragma unroll
            for (int r = 0; r < 4; ++r)
                part[mi][r] += vv * fast_tanh(qv + acc[mi][ni][r]);
        }
#pragma unroll
    for (int mi = 0; mi < 4; ++mi)
#pragma unroll
        for (int r = 0; r < 4; ++r) {
            float p = part[mi][r];
            p += __shfl_xor(p, 1);
            p += __shfl_xor(p, 2);
            p += __shfl_xor(p, 4);
            p += __shfl_xor(p, 8);
            if (lcol == 0) red[wm * 64 + mi * 16 + quad * 4 + r][we] = p;
        }
    __syncthreads();
    if (tid < 128) atomicAdd(&scores[b * NN + n0 + tid], red[tid][0] + red[tid][1]);
}

__global__ __launch_bounds__(256) void sm_fb(const float* __restrict__ scores,
                                             float* __restrict__ alpha,
                                             float* __restrict__ context) {
    const int b = blockIdx.x;
    const int t = threadIdx.x;
#pragma unroll
    for (int j = 0; j < 4; ++j) context[b * DD + t + 256 * j] = 0.f;
    float x[4];
    float m = -1e30f;
#pragma unroll
    for (int j = 0; j < 4; ++j) {
        x[j] = scores[b * NN + t + 256 * j];
        m = fmaxf(m, x[j]);
    }
#pragma unroll
    for (int mask = 32; mask >= 1; mask >>= 1) m = fmaxf(m, __shfl_xor(m, mask));
    __shared__ float wred[4];
    __shared__ float wsum[4];
    const int wv = t >> 6;
    if ((t & 63) == 0) wred[wv] = m;
    __syncthreads();
    m = fmaxf(fmaxf(wred[0], wred[1]), fmaxf(wred[2], wred[3]));
    float s = 0.f;
#pragma unroll
    for (int j = 0; j < 4; ++j) {
        x[j] = expf(x[j] - m);
        s += x[j];
    }
#pragma unroll
    for (int mask = 32; mask >= 1; mask >>= 1) s += __shfl_xor(s, mask);
    if ((t & 63) == 0) wsum[wv] = s;
    __syncthreads();
    s = wsum[0] + wsum[1] + wsum[2] + wsum[3];
    const float inv = 1.f / s;
#pragma unroll
    for (int j = 0; j < 4; ++j) alpha[b * NN + t + 256 * j] = x[j] * inv;
}

__global__ __launch_bounds__(256) void ctx_fb(const float* __restrict__ keys,
                                              const float* __restrict__ alpha,
                                              float* __restrict__ context) {
    const int b = blockIdx.y;
    const int nc = blockIdx.x;
    const int t = threadIdx.x;
    __shared__ float al[64];
    if (t < 64) al[t] = alpha[b * NN + nc * 64 + t];
    __syncthreads();
    const float4* kp = (const float4*)(keys + ((size_t)b * NN + nc * 64) * DD);
    float4 acc = {0.f, 0.f, 0.f, 0.f};
#pragma unroll 4
    for (int n = 0; n < 64; ++n) {
        const float a = al[n];
        float4 kv = kp[(size_t)n * (DD / 4) + t];
        acc.x = fmaf(a, kv.x, acc.x);
        acc.y = fmaf(a, kv.y, acc.y);
        acc.z = fmaf(a, kv.z, acc.z);
        acc.w = fmaf(a, kv.w, acc.w);
    }
    float* cp = context + b * DD + 4 * t;
    atomicAdd(cp + 0, acc.x);
    atomicAdd(cp + 1, acc.y);
    atomicAdd(cp + 2, acc.z);
    atomicAdd(cp + 3, acc.w);
}

extern "C" void kernel_launch(void* const* d_in, const int* in_sizes, int n_in,
                              void* d_out, int out_size, void* d_ws, size_t ws_size,
                              hipStream_t stream) {
    const float* h_t = (const float*)d_in[0];
    const float* keys = (const float*)d_in[1];
    const float* W_h = (const float*)d_in[2];
    const float* W_k = (const float*)d_in[3];
    const float* v = (const float*)d_in[4];

    float* context = (float*)d_out;          // [B, D]
    float* alpha = (float*)d_out + BB * DD;  // [B, N]
    float* qh = (float*)d_ws;                // [B, D]
    float* scores = (float*)d_ws + BB * DD;  // [B, N]

    const size_t wkT_off = (size_t)2 * BB * DD * sizeof(float);  // 512 KB
    const size_t need = wkT_off + (size_t)DD * DD * 2;           // +2 MB

    if (ws_size >= need) {
        _Float16* wkT = (_Float16*)((char*)d_ws + wkT_off);
        k_wk<<<dim3(8, 4), 256, 0, stream>>>(W_k, wkT);
        k_qh<<<dim3(64, 8), 256, 0, stream>>>(h_t, W_h, qh, scores);
        k_scf<<<dim3(64, 64), 256, 0, stream>>>(keys, wkT, v, qh, scores);
        k_sm<<<BB, 256, 0, stream>>>(scores, alpha);
        k_ctx<<<dim3(16, 64), 256, 0, stream>>>(keys, alpha, context);
    } else {
        qh_fb<<<dim3(4, BB), 256, 0, stream>>>(h_t, W_h, qh, scores);
        scores_fb<<<dim3(8, 512), 256, 0, stream>>>(keys, W_k, v, qh, scores);
        sm_fb<<<BB, 256, 0, stream>>>(scores, alpha, context);
        ctx_fb<<<dim3(16, BB), 256, 0, stream>>>(keys, alpha, context);
    }
}